// Round 4
// baseline (421.528 us; speedup 1.0000x reference)
//
#include <hip/hip_runtime.h>

#define HS   1024
#define SEQ  512
#define NBAT 64
#define INSZ 8
#define NM   4
#define DD   12
#define CH   16     // steps per P-chunk

#define ALPHA 0.1f
#define OMA   0.9f
#define SCL   (500.0f/1024.0f)
#define AS    (ALPHA*SCL)

// exp(2h) as exp2(GS*h) when native exp2 exists. A, B, ys all carry GS.
#if __has_builtin(__builtin_amdgcn_exp2f)
  #define GS 2.8853900817779268f      /* 2*log2(e) */
  #define EXPG(v) __builtin_amdgcn_exp2f(v)
#else
  #define GS 2.0f
  #define EXPG(v) __expf(v)
#endif

typedef float f2 __attribute__((ext_vector_type(2)));
typedef float f4 __attribute__((ext_vector_type(4)));
__device__ __forceinline__ f2 mk2(float a, float b){ f2 r; r.x=a; r.y=b; return r; }
__device__ __forceinline__ f2 splat2(float a){ return mk2(a,a); }
__device__ __forceinline__ f4 splat4(float a){ f4 r; r.x=a; r.y=a; r.z=a; r.w=a; return r; }
#if __has_builtin(__builtin_elementwise_fma)
__device__ __forceinline__ f2 fma2(f2 a, f2 b, f2 c){ return __builtin_elementwise_fma(a,b,c); }
__device__ __forceinline__ f4 fma4(f4 a, f4 b, f4 c){ return __builtin_elementwise_fma(a,b,c); }
#else
__device__ __forceinline__ f2 fma2(f2 a, f2 b, f2 c){
  f2 r; r.x=fmaf(a.x,b.x,c.x); r.y=fmaf(a.y,b.y,c.y); return r; }
__device__ __forceinline__ f4 fma4(f4 a, f4 b, f4 c){
  f4 r; r.x=fmaf(a.x,b.x,c.x); r.y=fmaf(a.y,b.y,c.y);
        r.z=fmaf(a.z,b.z,c.z); r.w=fmaf(a.w,b.w,c.w); return r; }
#endif

// DPP-based add: v += dpp_move(v). old=0 so masked/invalid lanes add 0.
#define DPP_ADD(v, ctrl, rmask, bmask) \
  v += __int_as_float(__builtin_amdgcn_update_dpp(0, __float_as_int(v), ctrl, rmask, bmask, true))

// Canonical gfx9 wave64 sum. Lane 63 holds the full 64-lane total afterwards.
__device__ __forceinline__ void wave64_sum2(float &a, float &b){
  DPP_ADD(a, 0x111, 0xf, 0xf); DPP_ADD(b, 0x111, 0xf, 0xf);  // row_shr:1
  DPP_ADD(a, 0x112, 0xf, 0xf); DPP_ADD(b, 0x112, 0xf, 0xf);  // row_shr:2
  DPP_ADD(a, 0x114, 0xf, 0xe); DPP_ADD(b, 0x114, 0xf, 0xe);  // row_shr:4
  DPP_ADD(a, 0x118, 0xf, 0xc); DPP_ADD(b, 0x118, 0xf, 0xc);  // row_shr:8
  DPP_ADD(a, 0x142, 0xa, 0xf); DPP_ADD(b, 0x142, 0xa, 0xf);  // row_bcast:15
  DPP_ADD(a, 0x143, 0xc, 0xf); DPP_ADD(b, 0x143, 0xc, 0xf);  // row_bcast:31
}
#define RD63(v) __int_as_float(__builtin_amdgcn_readlane(__float_as_int(v), 63))

// mixed[e] for unit i, e in [0,12). tril/means indices are compile-time after
// unrolling -> wave-uniform -> compiler emits s_load (SMEM), not VMEM.
__device__ __forceinline__ void mix_unit(int i, const float* __restrict__ eps,
                                         const float* __restrict__ means,
                                         const float* __restrict__ tril,
                                         const float* w, float* outm){
  float ep[NM][DD];
  #pragma unroll
  for (int k=0;k<NM;k++){
    const float4* p = (const float4*)(eps + (size_t)(k*HS + i)*DD);
    float4 r0=p[0], r1=p[1], r2=p[2];
    ep[k][0]=r0.x; ep[k][1]=r0.y; ep[k][2]=r0.z; ep[k][3]=r0.w;
    ep[k][4]=r1.x; ep[k][5]=r1.y; ep[k][6]=r1.z; ep[k][7]=r1.w;
    ep[k][8]=r2.x; ep[k][9]=r2.y; ep[k][10]=r2.z; ep[k][11]=r2.w;
  }
  #pragma unroll
  for (int e=0;e<DD;e++){
    float a = 0.f;
    #pragma unroll
    for (int k=0;k<NM;k++){
      float se = means[k*DD+e];
      #pragma unroll
      for (int d=0; d<e; d++) se = fmaf(ep[k][d], tril[(k*DD+e)*DD+d], se);
      float dg = fabsf(tril[(k*DD+e)*DD+e] - 1e-12f) + 1e-12f;
      se = fmaf(ep[k][e], dg, se);
      a = fmaf(w[k], se, a);
    }
    outm[e] = a;
  }
}

// Single-wave-per-batch scan, chunked: per 16-step chunk, a batched phase
// computes P[t][i] = I_i . Yg(t) into LDS (pure throughput, Iv registers are
// phase-local -> no spills), then the serial phase reads its own lane's P back
// (in-order DS, no barriers) with a 1-step ds_read prefetch.
__global__ __launch_bounds__(64,1)
void rnn_scan(const float* __restrict__ x, const float* __restrict__ eps,
              const float* __restrict__ means, const float* __restrict__ tril,
              const float* __restrict__ mw, float* __restrict__ out)
{
  const int b    = blockIdx.x;
  const int lane = threadIdx.x;            // 64 threads = 1 wave, 16 units/lane

  __shared__ float xs[SEQ*INSZ];                 // 16 KB
  __shared__ f4    ys4[SEQ][2];                  // 16 KB: Yg(t), GS-scaled
  __shared__ f4    Pb[CH][4][64];                // 64 KB: P chunk, lane-contig
  __shared__ f4    Ivl[4][8][64];                // 32 KB: I cols, lane-contig
  __shared__ __align__(16) float outb[SEQ*10];   // 20 KB   (total 148 KB)

  // stage x[b] early; loads fly under the preprocessing below
  { const f4* xp=(const f4*)(x + (size_t)b*SEQ*INSZ);
    f4* xd=(f4*)xs;
    for (int idx=lane; idx<SEQ*INSZ/4; idx+=64) xd[idx]=xp[idx]; }

  float w[NM];
  { float s=0.f;
    #pragma unroll
    for (int k=0;k<NM;k++){ w[k]=fmaxf(mw[k],1e-6f); s+=w[k]; }
    float inv=1.0f/s;
    #pragma unroll
    for (int k=0;k<NM;k++) w[k]*=inv; }

  // ---- preprocess: units 16*lane + 4*s + j; pair p = 2s+(j>>1), comp j&1 ----
  f2 m0v[8], m1v[8], n0v[8], n1v[8];
  float sn0=0.f, sn1=0.f;
  #pragma unroll
  for (int s=0;s<4;s++){
    f4 Irow[8];
    #pragma unroll
    for (int j=0;j<4;j++){
      float mm[DD];
      mix_unit(16*lane + 4*s + j, eps, means, tril, w, mm);
      const int p = 2*s + (j>>1);
      if ((j&1)==0){ m0v[p].x=mm[0]; m1v[p].x=mm[1];
                     n0v[p].x=-2.f*mm[2]; n1v[p].x=-2.f*mm[3]; }
      else         { m0v[p].y=mm[0]; m1v[p].y=mm[1];
                     n0v[p].y=-2.f*mm[2]; n1v[p].y=-2.f*mm[3]; }
      sn0 += mm[2]; sn1 += mm[3];
      #pragma unroll
      for (int e=0;e<8;e++) Irow[e][j] = mm[4+e];
    }
    #pragma unroll
    for (int e=0;e<8;e++) Ivl[s][e][lane] = Irow[e];
  }
  wave64_sum2(sn0, sn1);
  const float N0 = RD63(sn0), N1 = RD63(sn1);

  __syncthreads();   // xs staged, Ivl written (1 wave: ~free)

  // ---- ys: Yg at START of step t (folds x_0..x_{t-1}); verified gemm_c order
  if (lane < 8){
    float* ysf = (float*)ys4;
    float Y = 0.f;
    const float AG = GS*ALPHA;
    for (int t=0;t<SEQ;t++){
      ysf[t*8+lane] = Y;
      Y = fmaf(OMA, Y, AG*xs[t*8+lane]);
    }
  }
  __syncthreads();

  const float CA = GS*AS;
  float A=0.f, Bst=0.f, o=0.f;

  #define STEP(T, TN, c0,c1,c2,c3, d0,d1,d2,d3) { \
    d0=Pb[TN][0][lane]; d1=Pb[TN][1][lane]; d2=Pb[TN][2][lane]; d3=Pb[TN][3][lane]; \
    f2 g[8]; \
    g[0]=mk2(c0.x,c0.y); g[1]=mk2(c0.z,c0.w); \
    g[2]=mk2(c1.x,c1.y); g[3]=mk2(c1.z,c1.w); \
    g[4]=mk2(c2.x,c2.y); g[5]=mk2(c2.z,c2.w); \
    g[6]=mk2(c3.x,c3.y); g[7]=mk2(c3.z,c3.w); \
    { f2 A2=splat2(A), B2=splat2(Bst); \
      _Pragma("unroll") for (int p=0;p<8;p++){ \
        g[p]=fma2(m0v[p],A2,g[p]); g[p]=fma2(m1v[p],B2,g[p]); } } \
    f2 rr[8]; \
    _Pragma("unroll") for (int p=0;p<8;p++){ \
      f2 ex = mk2(EXPG(g[p].x), EXPG(g[p].y)); \
      f2 dd = mk2(ex.x+1.f, ex.y+1.f); \
      rr[p] = mk2(__builtin_amdgcn_rcpf(dd.x), __builtin_amdgcn_rcpf(dd.y)); } \
    f2 ua=mk2(0.f,0.f), ub=mk2(0.f,0.f), uc=mk2(0.f,0.f), ud=mk2(0.f,0.f); \
    _Pragma("unroll") for (int p=0;p<4;p++){ ua=fma2(rr[p],n0v[p],ua); ub=fma2(rr[p],n1v[p],ub); } \
    _Pragma("unroll") for (int p=4;p<8;p++){ uc=fma2(rr[p],n0v[p],uc); ud=fma2(rr[p],n1v[p],ud); } \
    float u0=(ua.x+ua.y)+(uc.x+uc.y); \
    float u1=(ub.x+ub.y)+(ud.x+ud.y); \
    wave64_sum2(u0,u1); \
    float U0 = N0 + RD63(u0); \
    float U1 = N1 + RD63(u1); \
    A   = fmaf(CA, U0, OMA*A); \
    Bst = fmaf(CA, U1, OMA*Bst); \
    if (lane<10){ \
      float add = lane==0 ? SCL*U0 : lane==1 ? SCL*U1 : xs[(T)*8+lane-2]; \
      o = fmaf(OMA, o, ALPHA*add); \
      outb[(T)*10+lane]=o; } \
  }

  #pragma unroll 1
  for (int c=0; c<SEQ/CH; c++){
    const int t0 = c*CH;

    // ---- phase A: P[tt][units] for this chunk (batched, latency-free) ----
    { f4 Iv4[4][8];
      #pragma unroll
      for (int s=0;s<4;s++)
        #pragma unroll
        for (int e=0;e<8;e++) Iv4[s][e] = Ivl[s][e][lane];
      #pragma unroll 2
      for (int tt=0; tt<CH; tt++){
        f4 ya = ys4[t0+tt][0], yb = ys4[t0+tt][1];   // wave-uniform broadcast
        #pragma unroll
        for (int s=0;s<4;s++){
          f4 acc =      Iv4[s][0]*splat4(ya.x);
          acc = fma4(Iv4[s][1], splat4(ya.y), acc);
          acc = fma4(Iv4[s][2], splat4(ya.z), acc);
          acc = fma4(Iv4[s][3], splat4(ya.w), acc);
          acc = fma4(Iv4[s][4], splat4(yb.x), acc);
          acc = fma4(Iv4[s][5], splat4(yb.y), acc);
          acc = fma4(Iv4[s][6], splat4(yb.z), acc);
          acc = fma4(Iv4[s][7], splat4(yb.w), acc);
          Pb[tt][s][lane] = acc;
        }
      }
    }

    // ---- phase B: serial scan over the chunk (reads own lane's P back) ----
    f4 cA0=Pb[0][0][lane], cA1=Pb[0][1][lane], cA2=Pb[0][2][lane], cA3=Pb[0][3][lane];
    f4 cB0,cB1,cB2,cB3;
    #pragma unroll 1
    for (int tt=0; tt<CH; tt+=2){
      STEP(t0+tt,   tt+1,        cA0,cA1,cA2,cA3, cB0,cB1,cB2,cB3)
      STEP(t0+tt+1, (tt+2)&(CH-1), cB0,cB1,cB2,cB3, cA0,cA1,cA2,cA3)
    }
  }
  #undef STEP

  __syncthreads();
  const f4* ob4 = (const f4*)outb;
  f4* o4 = (f4*)out + (size_t)b*(SEQ*10/4);
  for (int idx=lane; idx<SEQ*10/4; idx+=64) o4[idx]=ob4[idx];
}

extern "C" void kernel_launch(void* const* d_in, const int* in_sizes, int n_in,
                              void* d_out, int out_size, void* d_ws, size_t ws_size,
                              hipStream_t stream) {
  const float* x     = (const float*)d_in[0];  // (64,512,8)
  const float* eps   = (const float*)d_in[1];  // (4,1024,12)
  const float* means = (const float*)d_in[2];  // (4,12)
  const float* tril  = (const float*)d_in[3];  // (4,12,12)
  const float* mw    = (const float*)d_in[4];  // (4,)
  float* out = (float*)d_out;                  // (64,512,10) fp32

  rnn_scan<<<NBAT, 64, 0, stream>>>(x, eps, means, tril, mw, out);
}